// Round 3
// baseline (1032.486 us; speedup 1.0000x reference)
//
#include <hip/hip_runtime.h>
#include <stdint.h>

typedef __bf16 bf16;
typedef __bf16 bf16x8 __attribute__((ext_vector_type(8)));
typedef __bf16 bf16x4 __attribute__((ext_vector_type(4)));
typedef float  f32x4  __attribute__((ext_vector_type(4)));

#define B_   4
#define S_   1024
#define D_   1024
#define H_   16
#define DH_  64
#define DFF_ 4096
#define NL_  4
#define M_   (B_*S_)   // 4096 rows of activations

// ---------------------------------------------------------------------------
// async global->LDS copy, 16B per lane. LDS dest is wave-uniform base; lane i
// lands at base + i*16 bytes (guide §5 caveat).
// ---------------------------------------------------------------------------
__device__ __forceinline__ void async_copy16(const void* g, void* l) {
  __builtin_amdgcn_global_load_lds(
      (const __attribute__((address_space(1))) char*)(uintptr_t)g,
      (__attribute__((address_space(3))) char*)(uintptr_t)l,
      16, 0, 0);
}

#define WAITV8 asm volatile("s_waitcnt vmcnt(8)" ::: "memory")
#define WAITV4 asm volatile("s_waitcnt vmcnt(4)" ::: "memory")
#define WAITV0 asm volatile("s_waitcnt vmcnt(0)" ::: "memory")
#define BAR()  { asm volatile("" ::: "memory"); __builtin_amdgcn_s_barrier(); \
                 asm volatile("" ::: "memory"); }

// ---------------------------------------------------------------------------
// 256x256 phase-split pipelined GEMM (T2+T3+T4+T5), round-3 schedule:
// all 8 staging issues for tile t+1 happen at p0/p1 of tile t (issue-early),
// waits are vmcnt(8) end-p1 (kh1(t), issued 4-5 phases earlier) and vmcnt(4)
// end-p3 (kh0(t+1), issued 3 phases earlier) -> ~2x latency budget vs the
// round-1 schedule; never drains to 0 mid-loop.
// vmcnt ledger (steady state): enter p0 with 4 outstanding (kh1(t));
// p0 +4, p1 +4 -> 12; WAITV8 drains kh1(t). p3 WAITV4 drains kh0(t+1),
// leaving kh1(t+1)=4 in flight. Last tile: p1 WAITV0.
// MODE 1 = bf16 out + bias (+relu); QKV=1: bn>=2048 (V third) written
// transposed to Vt[b][h][64][S]. MODE 2 = *bf16* split-K partial (round 3)
// to Cb + kz*M*N.
// ---------------------------------------------------------------------------
template<int RELU, int MODE, int QKV>
__global__ __launch_bounds__(512, 2) void gemm256_kernel(
    const bf16* __restrict__ A,     // [M,Ktot] row-major bf16
    const bf16* __restrict__ W,     // [N,Ktot] row-major bf16
    const float* __restrict__ bias, // [N] (MODE 1)
    bf16*  __restrict__ Cb,         // MODE 1 out / MODE 2 bf16 partials
    bf16*  __restrict__ VtOut,      // QKV
    int N, int Ktot, int Kc, int gx, int PN, int PM, int bpk)
{
  __shared__ __align__(16) bf16 As[2][2][256*32];   // [buf][kk][row*32+c*8+e]
  __shared__ __align__(16) bf16 Bs[2][2][256*32];

  const int tid  = threadIdx.x;        // 0..511
  const int wave = tid >> 6;
  const int lane = tid & 63;
  const int wr = wave >> 2, wc = wave & 3;   // 2 x 4 wave grid
  const int q4  = lane >> 4;
  const int l15 = lane & 15;

  const int Lg  = blockIdx.x;
  const int kz  = Lg / bpk;
  const int L   = Lg % bpk;
  const int xcd = L & 7;
  const int s   = L >> 3;
  const int Gn  = gx / PN;
  const int bn = ((xcd % Gn)*PN + (s % PN)) << 8;
  const int bm = ((xcd / Gn)*PM + (s / PN)) << 8;
  const int kstart = kz * Kc;

  const int r_loc = lane >> 2, c4 = lane & 3;
  const int sko = (c4 ^ ((r_loc >> 1) & 3)) << 3;   // swizzled src k-offset
  const bf16* agp[2]; const bf16* wgp[2];
#pragma unroll
  for (int j = 0; j < 2; ++j) {
    const int rr = j*128 + wave*16 + r_loc;
    agp[j] = A + (size_t)(bm + rr)*Ktot + kstart + sko;
    wgp[j] = W + (size_t)(bn + rr)*Ktot + kstart + sko;
  }

  auto stageA = [&](int buf, int kk, int koff) {
#pragma unroll
    for (int j = 0; j < 2; ++j)
      async_copy16(agp[j] + koff + kk*32, &As[buf][kk][(j*128 + wave*16)*32]);
  };
  auto stageB = [&](int buf, int kk, int koff) {
#pragma unroll
    for (int j = 0; j < 2; ++j)
      async_copy16(wgp[j] + koff + kk*32, &Bs[buf][kk][(j*128 + wave*16)*32]);
  };

  const int ch = ((q4 ^ ((l15 >> 1) & 3)) << 3);

  f32x4 acc[8][4] = {};
  const int steps = Kc / 64;

  stageA(0, 0, 0); stageB(0, 0, 0); stageA(0, 1, 0); stageB(0, 1, 0);
  WAITV4;          // kh0 resident; kh1 (4 loads) still in flight
  BAR();

  int koff = 64;
  for (int t = 0; t < steps; ++t) {
    const int c = t & 1;
    const bool pf = (t + 1 < steps);
    bf16x8 bfr[4];
#pragma unroll
    for (int p = 0; p < 4; ++p) {
      const int kk = p >> 1, rh = p & 1;
      if (rh == 0) {
#pragma unroll
        for (int cf = 0; cf < 4; ++cf)
          bfr[cf] = *(const bf16x8*)&Bs[c][kk][(wc*64 + cf*16 + l15)*32 + ch];
      }
      bf16x8 af[4];
#pragma unroll
      for (int r4 = 0; r4 < 4; ++r4)
        af[r4] = *(const bf16x8*)&As[c][kk][(wr*128 + (rh*4 + r4)*16 + l15)*32 + ch];
      if (pf) {
        if      (p == 0) { stageA(c ^ 1, 0, koff); stageB(c ^ 1, 0, koff); }
        else if (p == 1) { stageA(c ^ 1, 1, koff); stageB(c ^ 1, 1, koff); }
      }
      BAR();
      __builtin_amdgcn_s_setprio(1);
#pragma unroll
      for (int r4 = 0; r4 < 4; ++r4)
#pragma unroll
        for (int cf = 0; cf < 4; ++cf)
          acc[rh*4 + r4][cf] = __builtin_amdgcn_mfma_f32_16x16x32_bf16(
              af[r4], bfr[cf], acc[rh*4 + r4][cf], 0, 0, 0);
      __builtin_amdgcn_s_setprio(0);
      if (p == 1) { if (pf) { WAITV8; } else { WAITV0; } }  // kh1(t) ready
      if (p == 3) { if (pf) { WAITV4; } }                   // kh0(t+1) ready
      BAR();
    }
    koff += 64;
  }

  // epilogue: C/D layout col=lane&15, row=q4*4+reg (m89-verified)
  if (QKV && bn >= 2*D_) {
#pragma unroll
    for (int r = 0; r < 8; ++r) {
      const int row0 = bm + wr*128 + r*16 + q4*4;
      const int bidx = row0 >> 10, s0 = row0 & 1023;
#pragma unroll
      for (int cf = 0; cf < 4; ++cf) {
        const int col  = bn + wc*64 + cf*16 + l15;
        const int dcol = col - 2*D_;
        const int hh = dcol >> 6, dd = dcol & 63;
        const float bv = bias[col];
        bf16x4 pk;
#pragma unroll
        for (int i = 0; i < 4; ++i) pk[i] = (bf16)(acc[r][cf][i] + bv);
        *(bf16x4*)&VtOut[((size_t)((bidx*H_ + hh)*64 + dd))*S_ + s0] = pk;
      }
    }
  } else if (MODE == 2) {
    bf16* Cpz = Cb + (size_t)kz * ((size_t)M_ * N);
#pragma unroll
    for (int r = 0; r < 8; ++r) {
      const int row0 = bm + wr*128 + r*16 + q4*4;
#pragma unroll
      for (int cf = 0; cf < 4; ++cf) {
        const int col = bn + wc*64 + cf*16 + l15;
#pragma unroll
        for (int i = 0; i < 4; ++i)
          Cpz[(size_t)(row0 + i)*N + col] = (bf16)acc[r][cf][i];
      }
    }
  } else {
#pragma unroll
    for (int r = 0; r < 8; ++r) {
      const int row0 = bm + wr*128 + r*16 + q4*4;
#pragma unroll
      for (int cf = 0; cf < 4; ++cf) {
        const int col = bn + wc*64 + cf*16 + l15;
        const float bv = bias[col];
#pragma unroll
        for (int i = 0; i < 4; ++i) {
          float v = acc[r][cf][i] + bv;
          if (RELU) v = fmaxf(v, 0.f);
          Cb[(size_t)(row0 + i)*N + col] = (bf16)v;
        }
      }
    }
  }
}

// ---------------------------------------------------------------------------
// 128x128 BK=64 split-K GEMM — kept for the small out-proj.
// MODE 2 now writes bf16 partials to Cb + kz*M*N.
// ---------------------------------------------------------------------------
template<int RELU, int MODE, int BK>
__global__ __launch_bounds__(256) void gemm_bt_kernel(
    const bf16* __restrict__ A, const bf16* __restrict__ W,
    const float* __restrict__ bias, bf16* __restrict__ Cb,
    int N, int Ktot, int Kc, int gx, int PN, int PM, int bpk)
{
  constexpr int NI = (BK == 64) ? 4 : 2;
  __shared__ bf16 As[2][128*BK];
  __shared__ bf16 Bs[2][128*BK];

  const int tid  = threadIdx.x;
  const int wave = tid >> 6;
  const int lane = tid & 63;
  const int wr = wave >> 1, wc = wave & 1;
  const int q4  = lane >> 4;
  const int l15 = lane & 15;

  const int Lg  = blockIdx.x;
  const int kz  = Lg / bpk;
  const int L   = Lg % bpk;
  const int xcd = L & 7;
  const int s   = L >> 3;
  const int Gn  = gx / PN;
  const int bn = ((xcd % Gn)*PN + (s % PN)) << 7;
  const int bm = ((xcd / Gn)*PM + (s / PN)) << 7;
  const int kstart = kz * Kc;

  const bf16* agp[NI]; const bf16* wgp[NI];
  int ldsb[NI];
  if constexpr (BK == 64) {
    const int r_loc = lane >> 3, c8 = lane & 7;
#pragma unroll
    for (int j = 0; j < NI; ++j) {
      const int rr = wave*32 + j*8 + r_loc;
      const int ko = ((c8 ^ (rr & 7)) << 3);
      agp[j] = A + (size_t)(bm + rr)*Ktot + kstart + ko;
      wgp[j] = W + (size_t)(bn + rr)*Ktot + kstart + ko;
      ldsb[j] = (wave*32 + j*8) * 64;
    }
  } else {
    const int r_loc = lane >> 2, c4 = lane & 3;
#pragma unroll
    for (int j = 0; j < NI; ++j) {
      const int rr = wave*32 + j*16 + r_loc;
      const int ko = ((c4 ^ ((rr >> 1) & 3)) << 3);
      agp[j] = A + (size_t)(bm + rr)*Ktot + kstart + ko;
      wgp[j] = W + (size_t)(bn + rr)*Ktot + kstart + ko;
      ldsb[j] = (wave*32 + j*16) * 32;
    }
  }

  f32x4 acc[4][4] = {};
  const int steps = Kc / BK;

  auto stage = [&](int buf) {
#pragma unroll
    for (int j = 0; j < NI; ++j) {
      async_copy16(agp[j], &As[buf][ldsb[j]]);
      async_copy16(wgp[j], &Bs[buf][ldsb[j]]);
      agp[j] += BK; wgp[j] += BK;
    }
  };

  const int sl32 = (l15 >> 1) & 3;
  const int sl64 = l15 & 7;

  auto compute = [&](int buf) {
    if constexpr (BK == 64) {
#pragma unroll
      for (int kk = 0; kk < 2; ++kk) {
        const int ch = (((kk << 2) | q4) ^ sl64) << 3;
        bf16x8 af[4], bfr[4];
#pragma unroll
        for (int rf = 0; rf < 4; ++rf)
          af[rf] = *(const bf16x8*)&As[buf][(wr*64 + rf*16 + l15)*64 + ch];
#pragma unroll
        for (int cf = 0; cf < 4; ++cf)
          bfr[cf] = *(const bf16x8*)&Bs[buf][(wc*64 + cf*16 + l15)*64 + ch];
#pragma unroll
        for (int rf = 0; rf < 4; ++rf)
#pragma unroll
          for (int cf = 0; cf < 4; ++cf)
            acc[rf][cf] = __builtin_amdgcn_mfma_f32_16x16x32_bf16(
                af[rf], bfr[cf], acc[rf][cf], 0, 0, 0);
      }
    } else {
      const int ch = (q4 ^ sl32) << 3;
      bf16x8 af[4], bfr[4];
#pragma unroll
      for (int rf = 0; rf < 4; ++rf)
        af[rf] = *(const bf16x8*)&As[buf][(wr*64 + rf*16 + l15)*32 + ch];
#pragma unroll
      for (int cf = 0; cf < 4; ++cf)
        bfr[cf] = *(const bf16x8*)&Bs[buf][(wc*64 + cf*16 + l15)*32 + ch];
#pragma unroll
      for (int rf = 0; rf < 4; ++rf)
#pragma unroll
        for (int cf = 0; cf < 4; ++cf)
          acc[rf][cf] = __builtin_amdgcn_mfma_f32_16x16x32_bf16(
              af[rf], bfr[cf], acc[rf][cf], 0, 0, 0);
    }
  };

  stage(0);
  __syncthreads();
  for (int k = 0; k < steps; ++k) {
    const int cur = k & 1;
    if (k + 1 < steps) stage(cur ^ 1);
    compute(cur);
    __syncthreads();
  }

  if (MODE == 2) {
    bf16* Cpz = Cb + (size_t)kz * ((size_t)M_ * N);
#pragma unroll
    for (int r = 0; r < 4; ++r) {
      const int row0 = bm + wr*64 + r*16 + q4*4;
#pragma unroll
      for (int c = 0; c < 4; ++c) {
        const int col = bn + wc*64 + c*16 + l15;
#pragma unroll
        for (int i = 0; i < 4; ++i)
          Cpz[(size_t)(row0 + i)*N + col] = (bf16)acc[r][c][i];
      }
    }
  } else {
#pragma unroll
    for (int r = 0; r < 4; ++r) {
      const int row0 = bm + wr*64 + r*16 + q4*4;
#pragma unroll
      for (int c = 0; c < 4; ++c) {
        const int col = bn + wc*64 + c*16 + l15;
        const float bv = bias[col];
#pragma unroll
        for (int i = 0; i < 4; ++i) {
          float v = acc[r][c][i] + bv;
          if (RELU) v = fmaxf(v, 0.f);
          Cb[(size_t)(row0 + i)*N + col] = (bf16)v;
        }
      }
    }
  }
}

// ---------------------------------------------------------------------------
// Flash-style block-causal attention (round-2 structure, unchanged):
// swapped QK^T in-register softmax, Q in regs, T13 defer-max, balanced
// qb-pair blocks. LDS 40960 B.
// ---------------------------------------------------------------------------
__global__ __launch_bounds__(256) void attn_kernel(
    const bf16* __restrict__ qkv,  // [M][3072]: Q at +0, K at +1024
    const bf16* __restrict__ vt,   // [B*H][64][S]
    bf16* __restrict__ out)        // [M][D]
{
  const int L    = blockIdx.x;           // 0..511
  const int xcd  = L & 7, slot = L >> 3; // slot 0..63
  const int qb0  = slot & 7;
  const int bh   = xcd*8 + (slot >> 3);
  const int b    = bh >> 4, h = bh & 15;
  const int tid  = threadIdx.x;
  const int wave = tid >> 6, lane = tid & 63;
  const int q4 = lane >> 4, l15 = lane & 15;
  const int r_loc = lane >> 3, c8 = lane & 7;

  __shared__ bf16 Ks[2][64*64];
  __shared__ bf16 Vs[2][64*64];
  __shared__ bf16 Ps[4][16*64];

  const size_t RS = 3*(size_t)D_;
  const bf16* kg = qkv + (size_t)(b*S_)*RS + D_ + h*64;
  const bf16* vg = vt + (size_t)bh*64*S_;

#define STAGE_KV(KT, BUF)                                              \
  {                                                                    \
    _Pragma("unroll")                                                  \
    for (int j = 0; j < 2; ++j) {                                      \
      const int rr = wave*16 + j*8 + r_loc;                            \
      const int ko = ((c8 ^ (rr & 7)) << 3);                           \
      async_copy16(kg + (size_t)((KT)*64 + rr)*RS + ko,                \
                   &Ks[BUF][(wave*16 + j*8)*64]);                      \
      async_copy16(vg + (size_t)rr*S_ + (KT)*64 + ko,                  \
                   &Vs[BUF][(wave*16 + j*8)*64]);                      \
    }                                                                  \
  }

  for (int pass = 0; pass < 2; ++pass) {
    const int qb = pass ? (15 - qb0) : qb0;
    const bf16* qg = qkv + (size_t)(b*S_ + qb*64)*RS + h*64;

    bf16x8 qf[2];
#pragma unroll
    for (int kk = 0; kk < 2; ++kk) {
      bf16x8 t = *(const bf16x8*)(qg + (size_t)(wave*16 + l15)*RS + kk*32 + (q4 << 3));
#pragma unroll
      for (int j = 0; j < 8; ++j) t[j] = (bf16)((float)t[j] * 0.125f);
      qf[kk] = t;
    }

    f32x4 o_acc[4] = {};
    float m_i = -1e30f, l_i = 0.f;

    STAGE_KV(0, 0)
    __syncthreads();

    for (int kt = 0; kt <= qb; ++kt) {
      const int cur = kt & 1;
      if (kt < qb) {
        if (cur) STAGE_KV(kt+1, 0) else STAGE_KV(kt+1, 1)
      }

      f32x4 sc[4] = {};
#pragma unroll
      for (int kk = 0; kk < 2; ++kk) {
        const int go = ((((kk << 2) | q4)) ^ (l15 & 7)) << 3;
#pragma unroll
        for (int m = 0; m < 4; ++m) {
          bf16x8 bk = *(const bf16x8*)&Ks[cur][(m*16 + l15)*64 + go];
          sc[m] = __builtin_amdgcn_mfma_f32_16x16x32_bf16(bk, qf[kk], sc[m], 0, 0, 0);
        }
      }

      float mx0 = fmaxf(fmaxf(sc[0][0], sc[0][1]), fmaxf(sc[0][2], sc[0][3]));
      float mx1 = fmaxf(fmaxf(sc[1][0], sc[1][1]), fmaxf(sc[1][2], sc[1][3]));
      float mx2 = fmaxf(fmaxf(sc[2][0], sc[2][1]), fmaxf(sc[2][2], sc[2][3]));
      float mx3 = fmaxf(fmaxf(sc[3][0], sc[3][1]), fmaxf(sc[3][2], sc[3][3]));
      float mx  = fmaxf(fmaxf(mx0, mx1), fmaxf(mx2, mx3));
      mx = fmaxf(mx, __shfl_xor(mx, 16, 64));
      mx = fmaxf(mx, __shfl_xor(mx, 32, 64));

      if (__any(mx > m_i + 8.f)) {
        const float m_new = fmaxf(m_i, mx);
        const float alpha = __expf(m_i - m_new);
        m_i = m_new;
        l_i *= alpha;
#pragma unroll
        for (int i = 0; i < 4; ++i) {
          const float av = __shfl(alpha, (lane & 48) | ((q4 << 2) | i), 64);
#pragma unroll
          for (int c = 0; c < 4; ++c) o_acc[c][i] *= av;
        }
      }

      float rs = 0.f;
#pragma unroll
      for (int m = 0; m < 4; ++m) {
        const float p0 = __expf(sc[m][0] - m_i);
        const float p1 = __expf(sc[m][1] - m_i);
        const float p2 = __expf(sc[m][2] - m_i);
        const float p3 = __expf(sc[m][3] - m_i);
        rs += (p0 + p1) + (p2 + p3);
        bf16x4 pk;
        pk[0] = (bf16)p0; pk[1] = (bf16)p1; pk[2] = (bf16)p2; pk[3] = (bf16)p3;
        const int cx = ((m << 2) | q4) ^ (l15 & 14);   // 8B-chunk swizzle
        *(bf16x4*)&Ps[wave][(l15 << 6) | (cx << 2)] = pk;
      }
      rs += __shfl_xor(rs, 16, 64);
      rs += __shfl_xor(rs, 32, 64);
      l_i += rs;

#pragma unroll
      for (int kk = 0; kk < 2; ++kk) {
        const int pcx = (((kk << 3) | (q4 << 1)) ^ (l15 & 14));
        bf16x8 ap = *(const bf16x8*)&Ps[wave][(l15 << 6) | (pcx << 2)];
        const int go = ((((kk << 2) | q4)) ^ (l15 & 7)) << 3;
#pragma unroll
        for (int c = 0; c < 4; ++c) {
          bf16x8 bv = *(const bf16x8*)&Vs[cur][(c*16 + l15)*64 + go];
          o_acc[c] = __builtin_amdgcn_mfma_f32_16x16x32_bf16(ap, bv, o_acc[c], 0, 0, 0);
        }
      }
      __syncthreads();
    }

    bf16* obase = out + ((size_t)(b*S_ + qb*64 + wave*16))*D_ + h*64;
#pragma unroll
    for (int i = 0; i < 4; ++i) {
      const float li = __shfl(l_i, (lane & 48) | ((q4 << 2) | i), 64);
      const float inv = 1.f / li;
#pragma unroll
      for (int c = 0; c < 4; ++c)
        obase[(size_t)((q4 << 2) | i)*D_ + c*16 + l15] = (bf16)(o_acc[c][i] * inv);
    }
  }
#undef STAGE_KV
}

// ---------------------------------------------------------------------------
// fused: split-K reduce (NP bf16 partials) + bias + residual + LayerNorm.
// Round 3: 4-contiguous-per-thread vectorized loads (float4 / bf16x4).
// ---------------------------------------------------------------------------
template<int NP>
__global__ __launch_bounds__(256) void add_ln_kernel(
    const float* __restrict__ xin, const bf16* __restrict__ parts,
    const float* __restrict__ ybias,
    const float* __restrict__ w, const float* __restrict__ bta,
    float* __restrict__ xout, bf16* __restrict__ xbf,
    float* __restrict__ extra)
{
  const int row = blockIdx.x;
  const int tid = threadIdx.x;
  const size_t base = (size_t)row * D_;
  const size_t PS = (size_t)M_ * D_;
  const int i0 = tid << 2;

  float4 xi = *(const float4*)&xin[base + i0];
  float4 yb = *(const float4*)&ybias[i0];
  float v[4] = { xi.x + yb.x, xi.y + yb.y, xi.z + yb.z, xi.w + yb.w };
#pragma unroll
  for (int pz = 0; pz < NP; ++pz) {
    bf16x4 pk = *(const bf16x4*)&parts[(size_t)pz*PS + base + i0];
#pragma unroll
    for (int i = 0; i < 4; ++i) v[i] += (float)pk[i];
  }
  float sm = (v[0] + v[1]) + (v[2] + v[3]);
  float ss = (v[0]*v[0] + v[1]*v[1]) + (v[2]*v[2] + v[3]*v[3]);
#pragma unroll
  for (int off = 1; off < 64; off <<= 1) {
    sm += __shfl_xor(sm, off, 64);
    ss += __shfl_xor(ss, off, 64);
  }
  __shared__ float red[8];
  const int wave = tid >> 6, lane = tid & 63;
  if (lane == 0) { red[wave] = sm; red[4 + wave] = ss; }
  __syncthreads();
  sm = red[0] + red[1] + red[2] + red[3];
  ss = red[4] + red[5] + red[6] + red[7];
  const float mean = sm * (1.f/D_);
  const float var  = ss * (1.f/D_) - mean*mean;
  const float rstd = rsqrtf(var + 1e-5f);

  float4 wv = *(const float4*)&w[i0];
  float4 bv = *(const float4*)&bta[i0];
  float o[4];
  o[0] = (v[0] - mean)*rstd*wv.x + bv.x;
  o[1] = (v[1] - mean)*rstd*wv.y + bv.y;
  o[2] = (v[2] - mean)*rstd*wv.z + bv.z;
  o[3] = (v[3] - mean)*rstd*wv.w + bv.w;
  float4 of = { o[0], o[1], o[2], o[3] };
  *(float4*)&xout[base + i0] = of;
  bf16x4 ob;
#pragma unroll
  for (int i = 0; i < 4; ++i) ob[i] = (bf16)o[i];
  *(bf16x4*)&xbf[base + i0] = ob;
  if (extra) *(float4*)&extra[base + i0] = of;
}

// ---------------------------------------------------------------------------
__global__ __launch_bounds__(256) void conv_kernel(
    const float4* __restrict__ src, bf16x4* __restrict__ dst, int n4)
{
  int i = blockIdx.x*blockDim.x + threadIdx.x;
  const int stride = gridDim.x*blockDim.x;
  for (; i < n4; i += stride) {
    float4 f = src[i];
    bf16x4 o;
    o[0] = (bf16)f.x; o[1] = (bf16)f.y; o[2] = (bf16)f.z; o[3] = (bf16)f.w;
    dst[i] = o;
  }
}

__global__ __launch_bounds__(256) void init_x_kernel(
    const float4* __restrict__ src, float4* __restrict__ xf,
    bf16x4* __restrict__ xb, int n4)
{
  int i = blockIdx.x*blockDim.x + threadIdx.x;
  const int stride = gridDim.x*blockDim.x;
  for (; i < n4; i += stride) {
    float4 f = src[i];
    xf[i] = f;
    bf16x4 o;
    o[0] = (bf16)f.x; o[1] = (bf16)f.y; o[2] = (bf16)f.z; o[3] = (bf16)f.w;
    xb[i] = o;
  }
}

// ---------------------------------------------------------------------------
extern "C" void kernel_launch(void* const* d_in, const int* in_sizes, int n_in,
                              void* d_out, int out_size, void* d_ws, size_t ws_size,
                              hipStream_t stream) {
  const float* x    = (const float*)d_in[0];
  const float* inw  = (const float*)d_in[1];
  const float* inb  = (const float*)d_in[2];
  const float* outw = (const float*)d_in[3];
  const float* outb = (const float*)d_in[4];
  const float* ln1w = (const float*)d_in[5];
  const float* ln1b = (const float*)d_in[6];
  const float* l1w  = (const float*)d_in[7];
  const float* l1b  = (const float*)d_in[8];
  const float* l2w  = (const float*)d_in[9];
  const float* l2b  = (const float*)d_in[10];
  const float* ln2w = (const float*)d_in[11];
  const float* ln2b = (const float*)d_in[12];

  char* ws = (char*)d_ws;
  size_t off = 0;
  auto take = [&](size_t bytes) {
    char* p = ws + off;
    off = (off + bytes + 255) & ~(size_t)255;
    return p;
  };
  bf16*  w_in_bf  = (bf16*) take((size_t)NL_*3*D_*D_*2);
  bf16*  w_out_bf = (bf16*) take((size_t)NL_*D_*D_*2);
  bf16*  w_l1_bf  = (bf16*) take((size_t)NL_*DFF_*D_*2);
  bf16*  w_l2_bf  = (bf16*) take((size_t)NL_*D_*DFF_*2);
  float* x_f      = (float*)take((size_t)M_*D_*4);
  bf16*  x_b      = (bf16*) take((size_t)M_*D_*2);
  bf16*  qkv_b    = (bf16*) take((size_t)M_*3*D_*2);
  bf16*  vt_b     = (bf16*) take((size_t)B_*H_*DH_*S_*2);
  bf16*  at_b     = (bf16*) take((size_t)M_*D_*2);
  bf16*  h_b      = (bf16*) take((size_t)M_*DFF_*2);
  bf16*  parts    = (bf16*) take((size_t)4*M_*D_*2);   // 4 bf16 partials
  (void)ws_size; (void)in_sizes; (void)n_in;

  auto conv = [&](const float* s, bf16* d, size_t n) {
    int n4 = (int)(n >> 2);
    int grid = (n4 + 255) / 256; if (grid > 4096) grid = 4096;
    conv_kernel<<<grid, 256, 0, stream>>>((const float4*)s, (bf16x4*)d, n4);
  };
  conv(inw,  w_in_bf,  (size_t)NL_*3*D_*D_);
  conv(outw, w_out_bf, (size_t)NL_*D_*D_);
  conv(l1w,  w_l1_bf,  (size_t)NL_*DFF_*D_);
  conv(l2w,  w_l2_bf,  (size_t)NL_*D_*DFF_);
  init_x_kernel<<<4096, 256, 0, stream>>>((const float4*)x, (float4*)x_f,
                                          (bf16x4*)x_b, (int)((size_t)M_*D_ >> 2));

  for (int l = 0; l < NL_; ++l) {
    // qkv = x @ in_proj_w^T + b [4096,3072]; 256^2 pipelined, 192 blocks;
    // V third -> Vt transposed
    gemm256_kernel<0,1,1><<<192, 512, 0, stream>>>(
        x_b, w_in_bf + (size_t)l*3*D_*D_, inb + (size_t)l*3*D_,
        qkv_b, vt_b, 3*D_, D_, D_, 12, 3, 8, 192);
    // attention -> at_b [4096,1024] bf16; 512 balanced blocks (qb pair/block)
    attn_kernel<<<512, 256, 0, stream>>>(qkv_b, vt_b, at_b);
    // o partials = attn @ out_w^T  (128^2 split-K=2, BK=64, grid 512)
    gemm_bt_kernel<0,2,64><<<512, 256, 0, stream>>>(
        at_b, w_out_bf + (size_t)l*D_*D_, nullptr,
        parts, D_, D_, D_/2, 8, 4, 8, 256);
    // x = LN(x + parts0 + parts1 + out_b)
    add_ln_kernel<2><<<M_, 256, 0, stream>>>(
        x_f, parts, outb + (size_t)l*D_,
        ln1w + (size_t)l*D_, ln1b + (size_t)l*D_, x_f, x_b, nullptr);
    // h = relu(x @ lin1^T + b) [4096,4096]; 256^2 pipelined, 256 blocks
    gemm256_kernel<1,1,0><<<256, 512, 0, stream>>>(
        x_b, w_l1_bf + (size_t)l*DFF_*D_, l1b + (size_t)l*DFF_,
        h_b, nullptr, DFF_, D_, D_, 16, 4, 8, 256);
    // f partials = h @ lin2^T  (256^2 split-K=4, Kc=1024, 256 blocks)
    gemm256_kernel<0,2,0><<<256, 512, 0, stream>>>(
        h_b, w_l2_bf + (size_t)l*D_*DFF_, nullptr,
        parts, nullptr, D_, DFF_, DFF_/4, 4, 1, 8, 64);
    // x = LN(x + parts0..3 + lin2_b); last layer writes d_out
    add_ln_kernel<4><<<M_, 256, 0, stream>>>(
        x_f, parts, l2b + (size_t)l*D_,
        ln2w + (size_t)l*D_, ln2b + (size_t)l*D_, x_f, x_b,
        (l == NL_-1) ? (float*)d_out : nullptr);
  }
}

// Round 4
// 975.881 us; speedup vs baseline: 1.0580x; 1.0580x over previous
//
#include <hip/hip_runtime.h>
#include <stdint.h>

typedef __bf16 bf16;
typedef __bf16 bf16x8 __attribute__((ext_vector_type(8)));
typedef __bf16 bf16x4 __attribute__((ext_vector_type(4)));
typedef float  f32x4  __attribute__((ext_vector_type(4)));

#define B_   4
#define S_   1024
#define D_   1024
#define H_   16
#define DH_  64
#define DFF_ 4096
#define NL_  4
#define M_   (B_*S_)   // 4096 rows of activations

// ---------------------------------------------------------------------------
// async global->LDS copy, 16B per lane. LDS dest is wave-uniform base; lane i
// lands at base + i*16 bytes (guide §5 caveat).
// ---------------------------------------------------------------------------
__device__ __forceinline__ void async_copy16(const void* g, void* l) {
  __builtin_amdgcn_global_load_lds(
      (const __attribute__((address_space(1))) char*)(uintptr_t)g,
      (__attribute__((address_space(3))) char*)(uintptr_t)l,
      16, 0, 0);
}

#define WAITV4 asm volatile("s_waitcnt vmcnt(4)" ::: "memory")
#define WAITV0 asm volatile("s_waitcnt vmcnt(0)" ::: "memory")
#define BAR()  { asm volatile("" ::: "memory"); __builtin_amdgcn_s_barrier(); \
                 asm volatile("" ::: "memory"); }

// ---------------------------------------------------------------------------
// 256x256 phase-split pipelined GEMM (T2+T3+T4+T5) — round-2 schedule
// (REVERTED from round-3 clustering: clustering put 12 loads in flight per
// wave and regressed FF1 48->57us; spread issue caps outstanding at 8).
// Per K-tile t (buf c), 4 phases; phase p: kk=p>>1, rh=p&1:
//   { ds_read frags ; stage ONE (matrix,k-half) pair of tile t+1 ;
//     barrier ; setprio(1) ; 16 MFMA ; setprio(0) ;
//     [p1: vmcnt(4) (last tile vmcnt(0))] [p3: vmcnt(4)] ; barrier }
// Stage order p0:A-kh0, p1:B-kh0, p2:A-kh1, p3:B-kh1 matches consumption;
// waits give each half-tile 2.5-3.5 phases of latency budget; max 8
// outstanding per wave; never drains to 0 mid-loop.
// MODE 1 = bf16 out + bias (+relu); QKV=1: bn>=2048 (V third) written
// transposed to Vt[b][h][64][S]. MODE 2 = bf16 split-K partial to Cb+kz*M*N.
// ---------------------------------------------------------------------------
template<int RELU, int MODE, int QKV>
__global__ __launch_bounds__(512, 2) void gemm256_kernel(
    const bf16* __restrict__ A,     // [M,Ktot] row-major bf16
    const bf16* __restrict__ W,     // [N,Ktot] row-major bf16
    const float* __restrict__ bias, // [N] (MODE 1)
    bf16*  __restrict__ Cb,         // MODE 1 out / MODE 2 bf16 partials
    bf16*  __restrict__ VtOut,      // QKV
    int N, int Ktot, int Kc, int gx, int PN, int PM, int bpk)
{
  __shared__ __align__(16) bf16 As[2][2][256*32];   // [buf][kk][row*32+c*8+e]
  __shared__ __align__(16) bf16 Bs[2][2][256*32];

  const int tid  = threadIdx.x;        // 0..511
  const int wave = tid >> 6;
  const int lane = tid & 63;
  const int wr = wave >> 2, wc = wave & 3;   // 2 x 4 wave grid
  const int q4  = lane >> 4;
  const int l15 = lane & 15;

  const int Lg  = blockIdx.x;
  const int kz  = Lg / bpk;
  const int L   = Lg % bpk;
  const int xcd = L & 7;
  const int s   = L >> 3;
  const int Gn  = gx / PN;
  const int bn = ((xcd % Gn)*PN + (s % PN)) << 8;
  const int bm = ((xcd / Gn)*PM + (s / PN)) << 8;
  const int kstart = kz * Kc;

  const int r_loc = lane >> 2, c4 = lane & 3;
  const int sko = (c4 ^ ((r_loc >> 1) & 3)) << 3;   // swizzled src k-offset
  const bf16* agp[2]; const bf16* wgp[2];
#pragma unroll
  for (int j = 0; j < 2; ++j) {
    const int rr = j*128 + wave*16 + r_loc;
    agp[j] = A + (size_t)(bm + rr)*Ktot + kstart + sko;
    wgp[j] = W + (size_t)(bn + rr)*Ktot + kstart + sko;
  }

  auto stageA = [&](int buf, int kk, int koff) {
#pragma unroll
    for (int j = 0; j < 2; ++j)
      async_copy16(agp[j] + koff + kk*32, &As[buf][kk][(j*128 + wave*16)*32]);
  };
  auto stageB = [&](int buf, int kk, int koff) {
#pragma unroll
    for (int j = 0; j < 2; ++j)
      async_copy16(wgp[j] + koff + kk*32, &Bs[buf][kk][(j*128 + wave*16)*32]);
  };

  const int ch = ((q4 ^ ((l15 >> 1) & 3)) << 3);

  f32x4 acc[8][4] = {};
  const int steps = Kc / 64;

  stageA(0, 0, 0); stageB(0, 0, 0); stageA(0, 1, 0); stageB(0, 1, 0);
  WAITV4;          // kh0 resident; kh1 (4 loads) still in flight
  BAR();

  int koff = 64;
  for (int t = 0; t < steps; ++t) {
    const int c = t & 1;
    const bool pf = (t + 1 < steps);
    bf16x8 bfr[4];
#pragma unroll
    for (int p = 0; p < 4; ++p) {
      const int kk = p >> 1, rh = p & 1;
      if (rh == 0) {
#pragma unroll
        for (int cf = 0; cf < 4; ++cf)
          bfr[cf] = *(const bf16x8*)&Bs[c][kk][(wc*64 + cf*16 + l15)*32 + ch];
      }
      bf16x8 af[4];
#pragma unroll
      for (int r4 = 0; r4 < 4; ++r4)
        af[r4] = *(const bf16x8*)&As[c][kk][(wr*128 + (rh*4 + r4)*16 + l15)*32 + ch];
      if (pf) {
        if      (p == 0) stageA(c ^ 1, 0, koff);
        else if (p == 1) stageB(c ^ 1, 0, koff);
        else if (p == 2) stageA(c ^ 1, 1, koff);
        else             stageB(c ^ 1, 1, koff);
      }
      BAR();
      __builtin_amdgcn_s_setprio(1);
#pragma unroll
      for (int r4 = 0; r4 < 4; ++r4)
#pragma unroll
        for (int cf = 0; cf < 4; ++cf)
          acc[rh*4 + r4][cf] = __builtin_amdgcn_mfma_f32_16x16x32_bf16(
              af[r4], bfr[cf], acc[rh*4 + r4][cf], 0, 0, 0);
      __builtin_amdgcn_s_setprio(0);
      if (p == 1) { if (pf) { WAITV4; } else { WAITV0; } }  // own kh1 ready
      if (p == 3) { if (pf) { WAITV4; } }                   // next kh0 ready
      BAR();
    }
    koff += 64;
  }

  // epilogue: C/D layout col=lane&15, row=q4*4+reg (m89-verified)
  if (QKV && bn >= 2*D_) {
#pragma unroll
    for (int r = 0; r < 8; ++r) {
      const int row0 = bm + wr*128 + r*16 + q4*4;
      const int bidx = row0 >> 10, s0 = row0 & 1023;
#pragma unroll
      for (int cf = 0; cf < 4; ++cf) {
        const int col  = bn + wc*64 + cf*16 + l15;
        const int dcol = col - 2*D_;
        const int hh = dcol >> 6, dd = dcol & 63;
        const float bv = bias[col];
        bf16x4 pk;
#pragma unroll
        for (int i = 0; i < 4; ++i) pk[i] = (bf16)(acc[r][cf][i] + bv);
        *(bf16x4*)&VtOut[((size_t)((bidx*H_ + hh)*64 + dd))*S_ + s0] = pk;
      }
    }
  } else if (MODE == 2) {
    bf16* Cpz = Cb + (size_t)kz * ((size_t)M_ * N);
#pragma unroll
    for (int r = 0; r < 8; ++r) {
      const int row0 = bm + wr*128 + r*16 + q4*4;
#pragma unroll
      for (int cf = 0; cf < 4; ++cf) {
        const int col = bn + wc*64 + cf*16 + l15;
#pragma unroll
        for (int i = 0; i < 4; ++i)
          Cpz[(size_t)(row0 + i)*N + col] = (bf16)acc[r][cf][i];
      }
    }
  } else {
#pragma unroll
    for (int r = 0; r < 8; ++r) {
      const int row0 = bm + wr*128 + r*16 + q4*4;
#pragma unroll
      for (int cf = 0; cf < 4; ++cf) {
        const int col = bn + wc*64 + cf*16 + l15;
        const float bv = bias[col];
#pragma unroll
        for (int i = 0; i < 4; ++i) {
          float v = acc[r][cf][i] + bv;
          if (RELU) v = fmaxf(v, 0.f);
          Cb[(size_t)(row0 + i)*N + col] = (bf16)v;
        }
      }
    }
  }
}

// ---------------------------------------------------------------------------
// 128x128 BK=64 split-K GEMM — kept for the small out-proj.
// MODE 2 writes bf16 partials to Cb + kz*M*N.
// ---------------------------------------------------------------------------
template<int RELU, int MODE, int BK>
__global__ __launch_bounds__(256) void gemm_bt_kernel(
    const bf16* __restrict__ A, const bf16* __restrict__ W,
    const float* __restrict__ bias, bf16* __restrict__ Cb,
    int N, int Ktot, int Kc, int gx, int PN, int PM, int bpk)
{
  constexpr int NI = (BK == 64) ? 4 : 2;
  __shared__ bf16 As[2][128*BK];
  __shared__ bf16 Bs[2][128*BK];

  const int tid  = threadIdx.x;
  const int wave = tid >> 6;
  const int lane = tid & 63;
  const int wr = wave >> 1, wc = wave & 1;
  const int q4  = lane >> 4;
  const int l15 = lane & 15;

  const int Lg  = blockIdx.x;
  const int kz  = Lg / bpk;
  const int L   = Lg % bpk;
  const int xcd = L & 7;
  const int s   = L >> 3;
  const int Gn  = gx / PN;
  const int bn = ((xcd % Gn)*PN + (s % PN)) << 7;
  const int bm = ((xcd / Gn)*PM + (s / PN)) << 7;
  const int kstart = kz * Kc;

  const bf16* agp[NI]; const bf16* wgp[NI];
  int ldsb[NI];
  if constexpr (BK == 64) {
    const int r_loc = lane >> 3, c8 = lane & 7;
#pragma unroll
    for (int j = 0; j < NI; ++j) {
      const int rr = wave*32 + j*8 + r_loc;
      const int ko = ((c8 ^ (rr & 7)) << 3);
      agp[j] = A + (size_t)(bm + rr)*Ktot + kstart + ko;
      wgp[j] = W + (size_t)(bn + rr)*Ktot + kstart + ko;
      ldsb[j] = (wave*32 + j*8) * 64;
    }
  } else {
    const int r_loc = lane >> 2, c4 = lane & 3;
#pragma unroll
    for (int j = 0; j < NI; ++j) {
      const int rr = wave*32 + j*16 + r_loc;
      const int ko = ((c4 ^ ((rr >> 1) & 3)) << 3);
      agp[j] = A + (size_t)(bm + rr)*Ktot + kstart + ko;
      wgp[j] = W + (size_t)(bn + rr)*Ktot + kstart + ko;
      ldsb[j] = (wave*32 + j*16) * 32;
    }
  }

  f32x4 acc[4][4] = {};
  const int steps = Kc / BK;

  auto stage = [&](int buf) {
#pragma unroll
    for (int j = 0; j < NI; ++j) {
      async_copy16(agp[j], &As[buf][ldsb[j]]);
      async_copy16(wgp[j], &Bs[buf][ldsb[j]]);
      agp[j] += BK; wgp[j] += BK;
    }
  };

  const int sl32 = (l15 >> 1) & 3;
  const int sl64 = l15 & 7;

  auto compute = [&](int buf) {
    if constexpr (BK == 64) {
#pragma unroll
      for (int kk = 0; kk < 2; ++kk) {
        const int ch = (((kk << 2) | q4) ^ sl64) << 3;
        bf16x8 af[4], bfr[4];
#pragma unroll
        for (int rf = 0; rf < 4; ++rf)
          af[rf] = *(const bf16x8*)&As[buf][(wr*64 + rf*16 + l15)*64 + ch];
#pragma unroll
        for (int cf = 0; cf < 4; ++cf)
          bfr[cf] = *(const bf16x8*)&Bs[buf][(wc*64 + cf*16 + l15)*64 + ch];
#pragma unroll
        for (int rf = 0; rf < 4; ++rf)
#pragma unroll
          for (int cf = 0; cf < 4; ++cf)
            acc[rf][cf] = __builtin_amdgcn_mfma_f32_16x16x32_bf16(
                af[rf], bfr[cf], acc[rf][cf], 0, 0, 0);
      }
    } else {
      const int ch = (q4 ^ sl32) << 3;
      bf16x8 af[4], bfr[4];
#pragma unroll
      for (int rf = 0; rf < 4; ++rf)
        af[rf] = *(const bf16x8*)&As[buf][(wr*64 + rf*16 + l15)*32 + ch];
#pragma unroll
      for (int cf = 0; cf < 4; ++cf)
        bfr[cf] = *(const bf16x8*)&Bs[buf][(wc*64 + cf*16 + l15)*32 + ch];
#pragma unroll
      for (int rf = 0; rf < 4; ++rf)
#pragma unroll
        for (int cf = 0; cf < 4; ++cf)
          acc[rf][cf] = __builtin_amdgcn_mfma_f32_16x16x32_bf16(
              af[rf], bfr[cf], acc[rf][cf], 0, 0, 0);
    }
  };

  stage(0);
  __syncthreads();
  for (int k = 0; k < steps; ++k) {
    const int cur = k & 1;
    if (k + 1 < steps) stage(cur ^ 1);
    compute(cur);
    __syncthreads();
  }

  if (MODE == 2) {
    bf16* Cpz = Cb + (size_t)kz * ((size_t)M_ * N);
#pragma unroll
    for (int r = 0; r < 4; ++r) {
      const int row0 = bm + wr*64 + r*16 + q4*4;
#pragma unroll
      for (int c = 0; c < 4; ++c) {
        const int col = bn + wc*64 + c*16 + l15;
#pragma unroll
        for (int i = 0; i < 4; ++i)
          Cpz[(size_t)(row0 + i)*N + col] = (bf16)acc[r][c][i];
      }
    }
  } else {
#pragma unroll
    for (int r = 0; r < 4; ++r) {
      const int row0 = bm + wr*64 + r*16 + q4*4;
#pragma unroll
      for (int c = 0; c < 4; ++c) {
        const int col = bn + wc*64 + c*16 + l15;
        const float bv = bias[col];
#pragma unroll
        for (int i = 0; i < 4; ++i) {
          float v = acc[r][c][i] + bv;
          if (RELU) v = fmaxf(v, 0.f);
          Cb[(size_t)(row0 + i)*N + col] = (bf16)v;
        }
      }
    }
  }
}

// ---------------------------------------------------------------------------
// Flash-style block-causal attention (round-2 structure, unchanged):
// swapped QK^T in-register softmax, Q in regs, T13 defer-max, balanced
// qb-pair blocks. LDS 40960 B.
// ---------------------------------------------------------------------------
__global__ __launch_bounds__(256) void attn_kernel(
    const bf16* __restrict__ qkv,  // [M][3072]: Q at +0, K at +1024
    const bf16* __restrict__ vt,   // [B*H][64][S]
    bf16* __restrict__ out)        // [M][D]
{
  const int L    = blockIdx.x;           // 0..511
  const int xcd  = L & 7, slot = L >> 3; // slot 0..63
  const int qb0  = slot & 7;
  const int bh   = xcd*8 + (slot >> 3);
  const int b    = bh >> 4, h = bh & 15;
  const int tid  = threadIdx.x;
  const int wave = tid >> 6, lane = tid & 63;
  const int q4 = lane >> 4, l15 = lane & 15;
  const int r_loc = lane >> 3, c8 = lane & 7;

  __shared__ bf16 Ks[2][64*64];
  __shared__ bf16 Vs[2][64*64];
  __shared__ bf16 Ps[4][16*64];

  const size_t RS = 3*(size_t)D_;
  const bf16* kg = qkv + (size_t)(b*S_)*RS + D_ + h*64;
  const bf16* vg = vt + (size_t)bh*64*S_;

#define STAGE_KV(KT, BUF)                                              \
  {                                                                    \
    _Pragma("unroll")                                                  \
    for (int j = 0; j < 2; ++j) {                                      \
      const int rr = wave*16 + j*8 + r_loc;                            \
      const int ko = ((c8 ^ (rr & 7)) << 3);                           \
      async_copy16(kg + (size_t)((KT)*64 + rr)*RS + ko,                \
                   &Ks[BUF][(wave*16 + j*8)*64]);                      \
      async_copy16(vg + (size_t)rr*S_ + (KT)*64 + ko,                  \
                   &Vs[BUF][(wave*16 + j*8)*64]);                      \
    }                                                                  \
  }

  for (int pass = 0; pass < 2; ++pass) {
    const int qb = pass ? (15 - qb0) : qb0;
    const bf16* qg = qkv + (size_t)(b*S_ + qb*64)*RS + h*64;

    bf16x8 qf[2];
#pragma unroll
    for (int kk = 0; kk < 2; ++kk) {
      bf16x8 t = *(const bf16x8*)(qg + (size_t)(wave*16 + l15)*RS + kk*32 + (q4 << 3));
#pragma unroll
      for (int j = 0; j < 8; ++j) t[j] = (bf16)((float)t[j] * 0.125f);
      qf[kk] = t;
    }

    f32x4 o_acc[4] = {};
    float m_i = -1e30f, l_i = 0.f;

    STAGE_KV(0, 0)
    __syncthreads();

    for (int kt = 0; kt <= qb; ++kt) {
      const int cur = kt & 1;
      if (kt < qb) {
        if (cur) STAGE_KV(kt+1, 0) else STAGE_KV(kt+1, 1)
      }

      f32x4 sc[4] = {};
#pragma unroll
      for (int kk = 0; kk < 2; ++kk) {
        const int go = ((((kk << 2) | q4)) ^ (l15 & 7)) << 3;
#pragma unroll
        for (int m = 0; m < 4; ++m) {
          bf16x8 bk = *(const bf16x8*)&Ks[cur][(m*16 + l15)*64 + go];
          sc[m] = __builtin_amdgcn_mfma_f32_16x16x32_bf16(bk, qf[kk], sc[m], 0, 0, 0);
        }
      }

      float mx0 = fmaxf(fmaxf(sc[0][0], sc[0][1]), fmaxf(sc[0][2], sc[0][3]));
      float mx1 = fmaxf(fmaxf(sc[1][0], sc[1][1]), fmaxf(sc[1][2], sc[1][3]));
      float mx2 = fmaxf(fmaxf(sc[2][0], sc[2][1]), fmaxf(sc[2][2], sc[2][3]));
      float mx3 = fmaxf(fmaxf(sc[3][0], sc[3][1]), fmaxf(sc[3][2], sc[3][3]));
      float mx  = fmaxf(fmaxf(mx0, mx1), fmaxf(mx2, mx3));
      mx = fmaxf(mx, __shfl_xor(mx, 16, 64));
      mx = fmaxf(mx, __shfl_xor(mx, 32, 64));

      if (__any(mx > m_i + 8.f)) {
        const float m_new = fmaxf(m_i, mx);
        const float alpha = __expf(m_i - m_new);
        m_i = m_new;
        l_i *= alpha;
#pragma unroll
        for (int i = 0; i < 4; ++i) {
          const float av = __shfl(alpha, (lane & 48) | ((q4 << 2) | i), 64);
#pragma unroll
          for (int c = 0; c < 4; ++c) o_acc[c][i] *= av;
        }
      }

      float rs = 0.f;
#pragma unroll
      for (int m = 0; m < 4; ++m) {
        const float p0 = __expf(sc[m][0] - m_i);
        const float p1 = __expf(sc[m][1] - m_i);
        const float p2 = __expf(sc[m][2] - m_i);
        const float p3 = __expf(sc[m][3] - m_i);
        rs += (p0 + p1) + (p2 + p3);
        bf16x4 pk;
        pk[0] = (bf16)p0; pk[1] = (bf16)p1; pk[2] = (bf16)p2; pk[3] = (bf16)p3;
        const int cx = ((m << 2) | q4) ^ (l15 & 14);   // 8B-chunk swizzle
        *(bf16x4*)&Ps[wave][(l15 << 6) | (cx << 2)] = pk;
      }
      rs += __shfl_xor(rs, 16, 64);
      rs += __shfl_xor(rs, 32, 64);
      l_i += rs;

#pragma unroll
      for (int kk = 0; kk < 2; ++kk) {
        const int pcx = (((kk << 3) | (q4 << 1)) ^ (l15 & 14));
        bf16x8 ap = *(const bf16x8*)&Ps[wave][(l15 << 6) | (pcx << 2)];
        const int go = ((((kk << 2) | q4)) ^ (l15 & 7)) << 3;
#pragma unroll
        for (int c = 0; c < 4; ++c) {
          bf16x8 bv = *(const bf16x8*)&Vs[cur][(c*16 + l15)*64 + go];
          o_acc[c] = __builtin_amdgcn_mfma_f32_16x16x32_bf16(ap, bv, o_acc[c], 0, 0, 0);
        }
      }
      __syncthreads();
    }

    bf16* obase = out + ((size_t)(b*S_ + qb*64 + wave*16))*D_ + h*64;
#pragma unroll
    for (int i = 0; i < 4; ++i) {
      const float li = __shfl(l_i, (lane & 48) | ((q4 << 2) | i), 64);
      const float inv = 1.f / li;
#pragma unroll
      for (int c = 0; c < 4; ++c)
        obase[(size_t)((q4 << 2) | i)*D_ + c*16 + l15] = (bf16)(o_acc[c][i] * inv);
    }
  }
#undef STAGE_KV
}

// ---------------------------------------------------------------------------
// fused: split-K reduce (NP bf16 partials) + bias + residual + LayerNorm.
// 4-contiguous-per-thread vectorized loads (float4 / bf16x4).
// ---------------------------------------------------------------------------
template<int NP>
__global__ __launch_bounds__(256) void add_ln_kernel(
    const float* __restrict__ xin, const bf16* __restrict__ parts,
    const float* __restrict__ ybias,
    const float* __restrict__ w, const float* __restrict__ bta,
    float* __restrict__ xout, bf16* __restrict__ xbf,
    float* __restrict__ extra)
{
  const int row = blockIdx.x;
  const int tid = threadIdx.x;
  const size_t base = (size_t)row * D_;
  const size_t PS = (size_t)M_ * D_;
  const int i0 = tid << 2;

  float4 xi = *(const float4*)&xin[base + i0];
  float4 yb = *(const float4*)&ybias[i0];
  float v[4] = { xi.x + yb.x, xi.y + yb.y, xi.z + yb.z, xi.w + yb.w };
#pragma unroll
  for (int pz = 0; pz < NP; ++pz) {
    bf16x4 pk = *(const bf16x4*)&parts[(size_t)pz*PS + base + i0];
#pragma unroll
    for (int i = 0; i < 4; ++i) v[i] += (float)pk[i];
  }
  float sm = (v[0] + v[1]) + (v[2] + v[3]);
  float ss = (v[0]*v[0] + v[1]*v[1]) + (v[2]*v[2] + v[3]*v[3]);
#pragma unroll
  for (int off = 1; off < 64; off <<= 1) {
    sm += __shfl_xor(sm, off, 64);
    ss += __shfl_xor(ss, off, 64);
  }
  __shared__ float red[8];
  const int wave = tid >> 6, lane = tid & 63;
  if (lane == 0) { red[wave] = sm; red[4 + wave] = ss; }
  __syncthreads();
  sm = red[0] + red[1] + red[2] + red[3];
  ss = red[4] + red[5] + red[6] + red[7];
  const float mean = sm * (1.f/D_);
  const float var  = ss * (1.f/D_) - mean*mean;
  const float rstd = rsqrtf(var + 1e-5f);

  float4 wv = *(const float4*)&w[i0];
  float4 bv = *(const float4*)&bta[i0];
  float o[4];
  o[0] = (v[0] - mean)*rstd*wv.x + bv.x;
  o[1] = (v[1] - mean)*rstd*wv.y + bv.y;
  o[2] = (v[2] - mean)*rstd*wv.z + bv.z;
  o[3] = (v[3] - mean)*rstd*wv.w + bv.w;
  float4 of = { o[0], o[1], o[2], o[3] };
  *(float4*)&xout[base + i0] = of;
  bf16x4 ob;
#pragma unroll
  for (int i = 0; i < 4; ++i) ob[i] = (bf16)o[i];
  *(bf16x4*)&xbf[base + i0] = ob;
  if (extra) *(float4*)&extra[base + i0] = of;
}

// ---------------------------------------------------------------------------
__global__ __launch_bounds__(256) void conv_kernel(
    const float4* __restrict__ src, bf16x4* __restrict__ dst, int n4)
{
  int i = blockIdx.x*blockDim.x + threadIdx.x;
  const int stride = gridDim.x*blockDim.x;
  for (; i < n4; i += stride) {
    float4 f = src[i];
    bf16x4 o;
    o[0] = (bf16)f.x; o[1] = (bf16)f.y; o[2] = (bf16)f.z; o[3] = (bf16)f.w;
    dst[i] = o;
  }
}

__global__ __launch_bounds__(256) void init_x_kernel(
    const float4* __restrict__ src, float4* __restrict__ xf,
    bf16x4* __restrict__ xb, int n4)
{
  int i = blockIdx.x*blockDim.x + threadIdx.x;
  const int stride = gridDim.x*blockDim.x;
  for (; i < n4; i += stride) {
    float4 f = src[i];
    xf[i] = f;
    bf16x4 o;
    o[0] = (bf16)f.x; o[1] = (bf16)f.y; o[2] = (bf16)f.z; o[3] = (bf16)f.w;
    xb[i] = o;
  }
}

// ---------------------------------------------------------------------------
extern "C" void kernel_launch(void* const* d_in, const int* in_sizes, int n_in,
                              void* d_out, int out_size, void* d_ws, size_t ws_size,
                              hipStream_t stream) {
  const float* x    = (const float*)d_in[0];
  const float* inw  = (const float*)d_in[1];
  const float* inb  = (const float*)d_in[2];
  const float* outw = (const float*)d_in[3];
  const float* outb = (const float*)d_in[4];
  const float* ln1w = (const float*)d_in[5];
  const float* ln1b = (const float*)d_in[6];
  const float* l1w  = (const float*)d_in[7];
  const float* l1b  = (const float*)d_in[8];
  const float* l2w  = (const float*)d_in[9];
  const float* l2b  = (const float*)d_in[10];
  const float* ln2w = (const float*)d_in[11];
  const float* ln2b = (const float*)d_in[12];

  char* ws = (char*)d_ws;
  size_t off = 0;
  auto take = [&](size_t bytes) {
    char* p = ws + off;
    off = (off + bytes + 255) & ~(size_t)255;
    return p;
  };
  bf16*  w_in_bf  = (bf16*) take((size_t)NL_*3*D_*D_*2);
  bf16*  w_out_bf = (bf16*) take((size_t)NL_*D_*D_*2);
  bf16*  w_l1_bf  = (bf16*) take((size_t)NL_*DFF_*D_*2);
  bf16*  w_l2_bf  = (bf16*) take((size_t)NL_*D_*DFF_*2);
  float* x_f      = (float*)take((size_t)M_*D_*4);
  bf16*  x_b      = (bf16*) take((size_t)M_*D_*2);
  bf16*  qkv_b    = (bf16*) take((size_t)M_*3*D_*2);
  bf16*  vt_b     = (bf16*) take((size_t)B_*H_*DH_*S_*2);
  bf16*  at_b     = (bf16*) take((size_t)M_*D_*2);
  bf16*  h_b      = (bf16*) take((size_t)M_*DFF_*2);
  bf16*  parts    = (bf16*) take((size_t)4*M_*D_*2);   // 4 bf16 partials
  (void)ws_size; (void)in_sizes; (void)n_in;

  auto conv = [&](const float* s, bf16* d, size_t n) {
    int n4 = (int)(n >> 2);
    int grid = (n4 + 255) / 256; if (grid > 4096) grid = 4096;
    conv_kernel<<<grid, 256, 0, stream>>>((const float4*)s, (bf16x4*)d, n4);
  };
  conv(inw,  w_in_bf,  (size_t)NL_*3*D_*D_);
  conv(outw, w_out_bf, (size_t)NL_*D_*D_);
  conv(l1w,  w_l1_bf,  (size_t)NL_*DFF_*D_);
  conv(l2w,  w_l2_bf,  (size_t)NL_*D_*DFF_);
  init_x_kernel<<<4096, 256, 0, stream>>>((const float4*)x, (float4*)x_f,
                                          (bf16x4*)x_b, (int)((size_t)M_*D_ >> 2));

  for (int l = 0; l < NL_; ++l) {
    // qkv = x @ in_proj_w^T + b [4096,3072]; 256^2 pipelined, 192 blocks;
    // V third -> Vt transposed
    gemm256_kernel<0,1,1><<<192, 512, 0, stream>>>(
        x_b, w_in_bf + (size_t)l*3*D_*D_, inb + (size_t)l*3*D_,
        qkv_b, vt_b, 3*D_, D_, D_, 12, 3, 8, 192);
    // attention -> at_b [4096,1024] bf16; 512 balanced blocks (qb pair/block)
    attn_kernel<<<512, 256, 0, stream>>>(qkv_b, vt_b, at_b);
    // o partials = attn @ out_w^T  (128^2 split-K=2, BK=64, grid 512)
    gemm_bt_kernel<0,2,64><<<512, 256, 0, stream>>>(
        at_b, w_out_bf + (size_t)l*D_*D_, nullptr,
        parts, D_, D_, D_/2, 8, 4, 8, 256);
    // x = LN(x + parts0 + parts1 + out_b)
    add_ln_kernel<2><<<M_, 256, 0, stream>>>(
        x_f, parts, outb + (size_t)l*D_,
        ln1w + (size_t)l*D_, ln1b + (size_t)l*D_, x_f, x_b, nullptr);
    // h = relu(x @ lin1^T + b) [4096,4096]; 256^2 pipelined, 256 blocks
    gemm256_kernel<1,1,0><<<256, 512, 0, stream>>>(
        x_b, w_l1_bf + (size_t)l*DFF_*D_, l1b + (size_t)l*DFF_,
        h_b, nullptr, DFF_, D_, D_, 16, 4, 8, 256);
    // f partials = h @ lin2^T  (256^2 split-K=4, Kc=1024, 256 blocks)
    gemm256_kernel<0,2,0><<<256, 512, 0, stream>>>(
        h_b, w_l2_bf + (size_t)l*D_*DFF_, nullptr,
        parts, nullptr, D_, DFF_, DFF_/4, 4, 1, 8, 64);
    // x = LN(x + parts0..3 + lin2_b); last layer writes d_out
    add_ln_kernel<4><<<M_, 256, 0, stream>>>(
        x_f, parts, l2b + (size_t)l*D_,
        ln2w + (size_t)l*D_, ln2b + (size_t)l*D_, x_f, x_b,
        (l == NL_-1) ? (float*)d_out : nullptr);
  }
}

// Round 5
// 964.003 us; speedup vs baseline: 1.0710x; 1.0123x over previous
//
#include <hip/hip_runtime.h>
#include <stdint.h>

typedef __bf16 bf16;
typedef __bf16 bf16x8 __attribute__((ext_vector_type(8)));
typedef __bf16 bf16x4 __attribute__((ext_vector_type(4)));
typedef float  f32x4  __attribute__((ext_vector_type(4)));

#define B_   4
#define S_   1024
#define D_   1024
#define H_   16
#define DH_  64
#define DFF_ 4096
#define NL_  4
#define M_   (B_*S_)   // 4096 rows of activations

// ---------------------------------------------------------------------------
// async global->LDS copy, 16B per lane. LDS dest is wave-uniform base; lane i
// lands at base + i*16 bytes (guide §5 caveat).
// ---------------------------------------------------------------------------
__device__ __forceinline__ void async_copy16(const void* g, void* l) {
  __builtin_amdgcn_global_load_lds(
      (const __attribute__((address_space(1))) char*)(uintptr_t)g,
      (__attribute__((address_space(3))) char*)(uintptr_t)l,
      16, 0, 0);
}

#define WAITV4 asm volatile("s_waitcnt vmcnt(4)" ::: "memory")
#define WAITV0 asm volatile("s_waitcnt vmcnt(0)" ::: "memory")
#define BAR()  { asm volatile("" ::: "memory"); __builtin_amdgcn_s_barrier(); \
                 asm volatile("" ::: "memory"); }

// ---------------------------------------------------------------------------
// 256x256 pipelined GEMM — round-5: TWO phases per K-tile (32 MFMA/phase).
// Round-4 counters showed each 4-phase block at ~1690cy/phase for 16 MFMA
// (m201 reference: ~825cy/phase) -> phase-fixed overhead dominates. Merging
// the two row-halves halves the barrier count (8->4 per K-tile) and
// amortizes the fixed cost over 2x the math.
// Phase kk of tile t (buf c):
//   { stage kh=kk of tile t+1 (A+B, 4 issues) ; ds_read bfr[4]+af[8] ;
//     BAR ; setprio(1) ; 32 MFMA (k-slice kk) ; setprio(0) ;
//     wait ; BAR }
// vmcnt ledger (steady): enter ph0 with 4 (kh1(t)); ph0 +4 -> 8, WAITV4
// drains kh1(t) [needed by ph1's ds_reads]; ph1 +4 -> 8, WAITV4 drains
// kh0(t+1) [needed by next ph0's ds_reads]. Last tile: ph0 WAITV0, ph1 none.
// Max 8 outstanding/wave (12 regressed in round 3); never drains to 0
// mid-loop. Swizzle (c4 ^ ((row>>1)&3), 0-conflict verified) unchanged.
// MODE 1 = bf16 out + bias (+relu); QKV=1: bn>=2048 (V third) written
// transposed to Vt[b][h][64][S]. MODE 2 = bf16 split-K partial to Cb+kz*M*N.
// ---------------------------------------------------------------------------
template<int RELU, int MODE, int QKV>
__global__ __launch_bounds__(512, 2) void gemm256_kernel(
    const bf16* __restrict__ A,     // [M,Ktot] row-major bf16
    const bf16* __restrict__ W,     // [N,Ktot] row-major bf16
    const float* __restrict__ bias, // [N] (MODE 1)
    bf16*  __restrict__ Cb,         // MODE 1 out / MODE 2 bf16 partials
    bf16*  __restrict__ VtOut,      // QKV
    int N, int Ktot, int Kc, int gx, int PN, int PM, int bpk)
{
  __shared__ __align__(16) bf16 As[2][2][256*32];   // [buf][kk][row*32+c*8+e]
  __shared__ __align__(16) bf16 Bs[2][2][256*32];

  const int tid  = threadIdx.x;        // 0..511
  const int wave = tid >> 6;
  const int lane = tid & 63;
  const int wr = wave >> 2, wc = wave & 3;   // 2 x 4 wave grid
  const int q4  = lane >> 4;
  const int l15 = lane & 15;

  const int Lg  = blockIdx.x;
  const int kz  = Lg / bpk;
  const int L   = Lg % bpk;
  const int xcd = L & 7;
  const int s   = L >> 3;
  const int Gn  = gx / PN;
  const int bn = ((xcd % Gn)*PN + (s % PN)) << 8;
  const int bm = ((xcd / Gn)*PM + (s / PN)) << 8;
  const int kstart = kz * Kc;

  const int r_loc = lane >> 2, c4 = lane & 3;
  const int sko = (c4 ^ ((r_loc >> 1) & 3)) << 3;   // swizzled src k-offset
  const bf16* agp[2]; const bf16* wgp[2];
#pragma unroll
  for (int j = 0; j < 2; ++j) {
    const int rr = j*128 + wave*16 + r_loc;
    agp[j] = A + (size_t)(bm + rr)*Ktot + kstart + sko;
    wgp[j] = W + (size_t)(bn + rr)*Ktot + kstart + sko;
  }

  auto stageA = [&](int buf, int kk, int koff) {
#pragma unroll
    for (int j = 0; j < 2; ++j)
      async_copy16(agp[j] + koff + kk*32, &As[buf][kk][(j*128 + wave*16)*32]);
  };
  auto stageB = [&](int buf, int kk, int koff) {
#pragma unroll
    for (int j = 0; j < 2; ++j)
      async_copy16(wgp[j] + koff + kk*32, &Bs[buf][kk][(j*128 + wave*16)*32]);
  };

  const int ch = ((q4 ^ ((l15 >> 1) & 3)) << 3);

  f32x4 acc[8][4] = {};
  const int steps = Kc / 64;

  // prologue: full tile 0 (8 loads), drain to 4 -> kh0 resident
  stageA(0, 0, 0); stageB(0, 0, 0); stageA(0, 1, 0); stageB(0, 1, 0);
  WAITV4;
  BAR();

  int koff = 64;
  for (int t = 0; t < steps; ++t) {
    const int c = t & 1;
    const bool pf = (t + 1 < steps);
#pragma unroll
    for (int kk = 0; kk < 2; ++kk) {
      if (pf) { stageA(c ^ 1, kk, koff); stageB(c ^ 1, kk, koff); }
      bf16x8 bfr[4];
#pragma unroll
      for (int cf = 0; cf < 4; ++cf)
        bfr[cf] = *(const bf16x8*)&Bs[c][kk][(wc*64 + cf*16 + l15)*32 + ch];
      bf16x8 af[8];
#pragma unroll
      for (int r = 0; r < 8; ++r)
        af[r] = *(const bf16x8*)&As[c][kk][(wr*128 + r*16 + l15)*32 + ch];
      BAR();
      __builtin_amdgcn_s_setprio(1);
#pragma unroll
      for (int r = 0; r < 8; ++r)
#pragma unroll
        for (int cf = 0; cf < 4; ++cf)
          acc[r][cf] = __builtin_amdgcn_mfma_f32_16x16x32_bf16(
              af[r], bfr[cf], acc[r][cf], 0, 0, 0);
      __builtin_amdgcn_s_setprio(0);
      if (kk == 0) { if (pf) { WAITV4; } else { WAITV0; } }  // kh1(t) ready
      else         { if (pf) { WAITV4; } }                   // kh0(t+1) ready
      BAR();
    }
    koff += 64;
  }

  // epilogue: C/D layout col=lane&15, row=q4*4+reg (m89-verified)
  if (QKV && bn >= 2*D_) {
#pragma unroll
    for (int r = 0; r < 8; ++r) {
      const int row0 = bm + wr*128 + r*16 + q4*4;
      const int bidx = row0 >> 10, s0 = row0 & 1023;
#pragma unroll
      for (int cf = 0; cf < 4; ++cf) {
        const int col  = bn + wc*64 + cf*16 + l15;
        const int dcol = col - 2*D_;
        const int hh = dcol >> 6, dd = dcol & 63;
        const float bv = bias[col];
        bf16x4 pk;
#pragma unroll
        for (int i = 0; i < 4; ++i) pk[i] = (bf16)(acc[r][cf][i] + bv);
        *(bf16x4*)&VtOut[((size_t)((bidx*H_ + hh)*64 + dd))*S_ + s0] = pk;
      }
    }
  } else if (MODE == 2) {
    bf16* Cpz = Cb + (size_t)kz * ((size_t)M_ * N);
#pragma unroll
    for (int r = 0; r < 8; ++r) {
      const int row0 = bm + wr*128 + r*16 + q4*4;
#pragma unroll
      for (int cf = 0; cf < 4; ++cf) {
        const int col = bn + wc*64 + cf*16 + l15;
#pragma unroll
        for (int i = 0; i < 4; ++i)
          Cpz[(size_t)(row0 + i)*N + col] = (bf16)acc[r][cf][i];
      }
    }
  } else {
#pragma unroll
    for (int r = 0; r < 8; ++r) {
      const int row0 = bm + wr*128 + r*16 + q4*4;
#pragma unroll
      for (int cf = 0; cf < 4; ++cf) {
        const int col = bn + wc*64 + cf*16 + l15;
        const float bv = bias[col];
#pragma unroll
        for (int i = 0; i < 4; ++i) {
          float v = acc[r][cf][i] + bv;
          if (RELU) v = fmaxf(v, 0.f);
          Cb[(size_t)(row0 + i)*N + col] = (bf16)v;
        }
      }
    }
  }
}

// ---------------------------------------------------------------------------
// 128x128 BK=64 split-K GEMM — kept for the small out-proj.
// MODE 2 writes bf16 partials to Cb + kz*M*N.
// ---------------------------------------------------------------------------
template<int RELU, int MODE, int BK>
__global__ __launch_bounds__(256) void gemm_bt_kernel(
    const bf16* __restrict__ A, const bf16* __restrict__ W,
    const float* __restrict__ bias, bf16* __restrict__ Cb,
    int N, int Ktot, int Kc, int gx, int PN, int PM, int bpk)
{
  constexpr int NI = (BK == 64) ? 4 : 2;
  __shared__ bf16 As[2][128*BK];
  __shared__ bf16 Bs[2][128*BK];

  const int tid  = threadIdx.x;
  const int wave = tid >> 6;
  const int lane = tid & 63;
  const int wr = wave >> 1, wc = wave & 1;
  const int q4  = lane >> 4;
  const int l15 = lane & 15;

  const int Lg  = blockIdx.x;
  const int kz  = Lg / bpk;
  const int L   = Lg % bpk;
  const int xcd = L & 7;
  const int s   = L >> 3;
  const int Gn  = gx / PN;
  const int bn = ((xcd % Gn)*PN + (s % PN)) << 7;
  const int bm = ((xcd / Gn)*PM + (s / PN)) << 7;
  const int kstart = kz * Kc;

  const bf16* agp[NI]; const bf16* wgp[NI];
  int ldsb[NI];
  if constexpr (BK == 64) {
    const int r_loc = lane >> 3, c8 = lane & 7;
#pragma unroll
    for (int j = 0; j < NI; ++j) {
      const int rr = wave*32 + j*8 + r_loc;
      const int ko = ((c8 ^ (rr & 7)) << 3);
      agp[j] = A + (size_t)(bm + rr)*Ktot + kstart + ko;
      wgp[j] = W + (size_t)(bn + rr)*Ktot + kstart + ko;
      ldsb[j] = (wave*32 + j*8) * 64;
    }
  } else {
    const int r_loc = lane >> 2, c4 = lane & 3;
#pragma unroll
    for (int j = 0; j < NI; ++j) {
      const int rr = wave*32 + j*16 + r_loc;
      const int ko = ((c4 ^ ((rr >> 1) & 3)) << 3);
      agp[j] = A + (size_t)(bm + rr)*Ktot + kstart + ko;
      wgp[j] = W + (size_t)(bn + rr)*Ktot + kstart + ko;
      ldsb[j] = (wave*32 + j*16) * 32;
    }
  }

  f32x4 acc[4][4] = {};
  const int steps = Kc / BK;

  auto stage = [&](int buf) {
#pragma unroll
    for (int j = 0; j < NI; ++j) {
      async_copy16(agp[j], &As[buf][ldsb[j]]);
      async_copy16(wgp[j], &Bs[buf][ldsb[j]]);
      agp[j] += BK; wgp[j] += BK;
    }
  };

  const int sl32 = (l15 >> 1) & 3;
  const int sl64 = l15 & 7;

  auto compute = [&](int buf) {
    if constexpr (BK == 64) {
#pragma unroll
      for (int kk = 0; kk < 2; ++kk) {
        const int ch = (((kk << 2) | q4) ^ sl64) << 3;
        bf16x8 af[4], bfr[4];
#pragma unroll
        for (int rf = 0; rf < 4; ++rf)
          af[rf] = *(const bf16x8*)&As[buf][(wr*64 + rf*16 + l15)*64 + ch];
#pragma unroll
        for (int cf = 0; cf < 4; ++cf)
          bfr[cf] = *(const bf16x8*)&Bs[buf][(wc*64 + cf*16 + l15)*64 + ch];
#pragma unroll
        for (int rf = 0; rf < 4; ++rf)
#pragma unroll
          for (int cf = 0; cf < 4; ++cf)
            acc[rf][cf] = __builtin_amdgcn_mfma_f32_16x16x32_bf16(
                af[rf], bfr[cf], acc[rf][cf], 0, 0, 0);
      }
    } else {
      const int ch = (q4 ^ sl32) << 3;
      bf16x8 af[4], bfr[4];
#pragma unroll
      for (int rf = 0; rf < 4; ++rf)
        af[rf] = *(const bf16x8*)&As[buf][(wr*64 + rf*16 + l15)*32 + ch];
#pragma unroll
      for (int cf = 0; cf < 4; ++cf)
        bfr[cf] = *(const bf16x8*)&Bs[buf][(wc*64 + cf*16 + l15)*32 + ch];
#pragma unroll
      for (int rf = 0; rf < 4; ++rf)
#pragma unroll
        for (int cf = 0; cf < 4; ++cf)
          acc[rf][cf] = __builtin_amdgcn_mfma_f32_16x16x32_bf16(
              af[rf], bfr[cf], acc[rf][cf], 0, 0, 0);
    }
  };

  stage(0);
  __syncthreads();
  for (int k = 0; k < steps; ++k) {
    const int cur = k & 1;
    if (k + 1 < steps) stage(cur ^ 1);
    compute(cur);
    __syncthreads();
  }

  if (MODE == 2) {
    bf16* Cpz = Cb + (size_t)kz * ((size_t)M_ * N);
#pragma unroll
    for (int r = 0; r < 4; ++r) {
      const int row0 = bm + wr*64 + r*16 + q4*4;
#pragma unroll
      for (int c = 0; c < 4; ++c) {
        const int col = bn + wc*64 + c*16 + l15;
#pragma unroll
        for (int i = 0; i < 4; ++i)
          Cpz[(size_t)(row0 + i)*N + col] = (bf16)acc[r][c][i];
      }
    }
  } else {
#pragma unroll
    for (int r = 0; r < 4; ++r) {
      const int row0 = bm + wr*64 + r*16 + q4*4;
#pragma unroll
      for (int c = 0; c < 4; ++c) {
        const int col = bn + wc*64 + c*16 + l15;
        const float bv = bias[col];
#pragma unroll
        for (int i = 0; i < 4; ++i) {
          float v = acc[r][c][i] + bv;
          if (RELU) v = fmaxf(v, 0.f);
          Cb[(size_t)(row0 + i)*N + col] = (bf16)v;
        }
      }
    }
  }
}

// ---------------------------------------------------------------------------
// Flash-style block-causal attention (round-2 structure, unchanged):
// swapped QK^T in-register softmax, Q in regs, T13 defer-max, balanced
// qb-pair blocks. LDS 40960 B.
// ---------------------------------------------------------------------------
__global__ __launch_bounds__(256) void attn_kernel(
    const bf16* __restrict__ qkv,  // [M][3072]: Q at +0, K at +1024
    const bf16* __restrict__ vt,   // [B*H][64][S]
    bf16* __restrict__ out)        // [M][D]
{
  const int L    = blockIdx.x;           // 0..511
  const int xcd  = L & 7, slot = L >> 3; // slot 0..63
  const int qb0  = slot & 7;
  const int bh   = xcd*8 + (slot >> 3);
  const int b    = bh >> 4, h = bh & 15;
  const int tid  = threadIdx.x;
  const int wave = tid >> 6, lane = tid & 63;
  const int q4 = lane >> 4, l15 = lane & 15;
  const int r_loc = lane >> 3, c8 = lane & 7;

  __shared__ bf16 Ks[2][64*64];
  __shared__ bf16 Vs[2][64*64];
  __shared__ bf16 Ps[4][16*64];

  const size_t RS = 3*(size_t)D_;
  const bf16* kg = qkv + (size_t)(b*S_)*RS + D_ + h*64;
  const bf16* vg = vt + (size_t)bh*64*S_;

#define STAGE_KV(KT, BUF)                                              \
  {                                                                    \
    _Pragma("unroll")                                                  \
    for (int j = 0; j < 2; ++j) {                                      \
      const int rr = wave*16 + j*8 + r_loc;                            \
      const int ko = ((c8 ^ (rr & 7)) << 3);                           \
      async_copy16(kg + (size_t)((KT)*64 + rr)*RS + ko,                \
                   &Ks[BUF][(wave*16 + j*8)*64]);                      \
      async_copy16(vg + (size_t)rr*S_ + (KT)*64 + ko,                  \
                   &Vs[BUF][(wave*16 + j*8)*64]);                      \
    }                                                                  \
  }

  for (int pass = 0; pass < 2; ++pass) {
    const int qb = pass ? (15 - qb0) : qb0;
    const bf16* qg = qkv + (size_t)(b*S_ + qb*64)*RS + h*64;

    bf16x8 qf[2];
#pragma unroll
    for (int kk = 0; kk < 2; ++kk) {
      bf16x8 t = *(const bf16x8*)(qg + (size_t)(wave*16 + l15)*RS + kk*32 + (q4 << 3));
#pragma unroll
      for (int j = 0; j < 8; ++j) t[j] = (bf16)((float)t[j] * 0.125f);
      qf[kk] = t;
    }

    f32x4 o_acc[4] = {};
    float m_i = -1e30f, l_i = 0.f;

    STAGE_KV(0, 0)
    __syncthreads();

    for (int kt = 0; kt <= qb; ++kt) {
      const int cur = kt & 1;
      if (kt < qb) {
        if (cur) STAGE_KV(kt+1, 0) else STAGE_KV(kt+1, 1)
      }

      f32x4 sc[4] = {};
#pragma unroll
      for (int kk = 0; kk < 2; ++kk) {
        const int go = ((((kk << 2) | q4)) ^ (l15 & 7)) << 3;
#pragma unroll
        for (int m = 0; m < 4; ++m) {
          bf16x8 bk = *(const bf16x8*)&Ks[cur][(m*16 + l15)*64 + go];
          sc[m] = __builtin_amdgcn_mfma_f32_16x16x32_bf16(bk, qf[kk], sc[m], 0, 0, 0);
        }
      }

      float mx0 = fmaxf(fmaxf(sc[0][0], sc[0][1]), fmaxf(sc[0][2], sc[0][3]));
      float mx1 = fmaxf(fmaxf(sc[1][0], sc[1][1]), fmaxf(sc[1][2], sc[1][3]));
      float mx2 = fmaxf(fmaxf(sc[2][0], sc[2][1]), fmaxf(sc[2][2], sc[2][3]));
      float mx3 = fmaxf(fmaxf(sc[3][0], sc[3][1]), fmaxf(sc[3][2], sc[3][3]));
      float mx  = fmaxf(fmaxf(mx0, mx1), fmaxf(mx2, mx3));
      mx = fmaxf(mx, __shfl_xor(mx, 16, 64));
      mx = fmaxf(mx, __shfl_xor(mx, 32, 64));

      if (__any(mx > m_i + 8.f)) {
        const float m_new = fmaxf(m_i, mx);
        const float alpha = __expf(m_i - m_new);
        m_i = m_new;
        l_i *= alpha;
#pragma unroll
        for (int i = 0; i < 4; ++i) {
          const float av = __shfl(alpha, (lane & 48) | ((q4 << 2) | i), 64);
#pragma unroll
          for (int c = 0; c < 4; ++c) o_acc[c][i] *= av;
        }
      }

      float rs = 0.f;
#pragma unroll
      for (int m = 0; m < 4; ++m) {
        const float p0 = __expf(sc[m][0] - m_i);
        const float p1 = __expf(sc[m][1] - m_i);
        const float p2 = __expf(sc[m][2] - m_i);
        const float p3 = __expf(sc[m][3] - m_i);
        rs += (p0 + p1) + (p2 + p3);
        bf16x4 pk;
        pk[0] = (bf16)p0; pk[1] = (bf16)p1; pk[2] = (bf16)p2; pk[3] = (bf16)p3;
        const int cx = ((m << 2) | q4) ^ (l15 & 14);   // 8B-chunk swizzle
        *(bf16x4*)&Ps[wave][(l15 << 6) | (cx << 2)] = pk;
      }
      rs += __shfl_xor(rs, 16, 64);
      rs += __shfl_xor(rs, 32, 64);
      l_i += rs;

#pragma unroll
      for (int kk = 0; kk < 2; ++kk) {
        const int pcx = (((kk << 3) | (q4 << 1)) ^ (l15 & 14));
        bf16x8 ap = *(const bf16x8*)&Ps[wave][(l15 << 6) | (pcx << 2)];
        const int go = ((((kk << 2) | q4)) ^ (l15 & 7)) << 3;
#pragma unroll
        for (int c = 0; c < 4; ++c) {
          bf16x8 bv = *(const bf16x8*)&Vs[cur][(c*16 + l15)*64 + go];
          o_acc[c] = __builtin_amdgcn_mfma_f32_16x16x32_bf16(ap, bv, o_acc[c], 0, 0, 0);
        }
      }
      __syncthreads();
    }

    bf16* obase = out + ((size_t)(b*S_ + qb*64 + wave*16))*D_ + h*64;
#pragma unroll
    for (int i = 0; i < 4; ++i) {
      const float li = __shfl(l_i, (lane & 48) | ((q4 << 2) | i), 64);
      const float inv = 1.f / li;
#pragma unroll
      for (int c = 0; c < 4; ++c)
        obase[(size_t)((q4 << 2) | i)*D_ + c*16 + l15] = (bf16)(o_acc[c][i] * inv);
    }
  }
#undef STAGE_KV
}

// ---------------------------------------------------------------------------
// fused: split-K reduce (NP bf16 partials) + bias + residual + LayerNorm.
// 4-contiguous-per-thread vectorized loads (float4 / bf16x4).
// ---------------------------------------------------------------------------
template<int NP>
__global__ __launch_bounds__(256) void add_ln_kernel(
    const float* __restrict__ xin, const bf16* __restrict__ parts,
    const float* __restrict__ ybias,
    const float* __restrict__ w, const float* __restrict__ bta,
    float* __restrict__ xout, bf16* __restrict__ xbf,
    float* __restrict__ extra)
{
  const int row = blockIdx.x;
  const int tid = threadIdx.x;
  const size_t base = (size_t)row * D_;
  const size_t PS = (size_t)M_ * D_;
  const int i0 = tid << 2;

  float4 xi = *(const float4*)&xin[base + i0];
  float4 yb = *(const float4*)&ybias[i0];
  float v[4] = { xi.x + yb.x, xi.y + yb.y, xi.z + yb.z, xi.w + yb.w };
#pragma unroll
  for (int pz = 0; pz < NP; ++pz) {
    bf16x4 pk = *(const bf16x4*)&parts[(size_t)pz*PS + base + i0];
#pragma unroll
    for (int i = 0; i < 4; ++i) v[i] += (float)pk[i];
  }
  float sm = (v[0] + v[1]) + (v[2] + v[3]);
  float ss = (v[0]*v[0] + v[1]*v[1]) + (v[2]*v[2] + v[3]*v[3]);
#pragma unroll
  for (int off = 1; off < 64; off <<= 1) {
    sm += __shfl_xor(sm, off, 64);
    ss += __shfl_xor(ss, off, 64);
  }
  __shared__ float red[8];
  const int wave = tid >> 6, lane = tid & 63;
  if (lane == 0) { red[wave] = sm; red[4 + wave] = ss; }
  __syncthreads();
  sm = red[0] + red[1] + red[2] + red[3];
  ss = red[4] + red[5] + red[6] + red[7];
  const float mean = sm * (1.f/D_);
  const float var  = ss * (1.f/D_) - mean*mean;
  const float rstd = rsqrtf(var + 1e-5f);

  float4 wv = *(const float4*)&w[i0];
  float4 bv = *(const float4*)&bta[i0];
  float o[4];
  o[0] = (v[0] - mean)*rstd*wv.x + bv.x;
  o[1] = (v[1] - mean)*rstd*wv.y + bv.y;
  o[2] = (v[2] - mean)*rstd*wv.z + bv.z;
  o[3] = (v[3] - mean)*rstd*wv.w + bv.w;
  float4 of = { o[0], o[1], o[2], o[3] };
  *(float4*)&xout[base + i0] = of;
  bf16x4 ob;
#pragma unroll
  for (int i = 0; i < 4; ++i) ob[i] = (bf16)o[i];
  *(bf16x4*)&xbf[base + i0] = ob;
  if (extra) *(float4*)&extra[base + i0] = of;
}

// ---------------------------------------------------------------------------
__global__ __launch_bounds__(256) void conv_kernel(
    const float4* __restrict__ src, bf16x4* __restrict__ dst, int n4)
{
  int i = blockIdx.x*blockDim.x + threadIdx.x;
  const int stride = gridDim.x*blockDim.x;
  for (; i < n4; i += stride) {
    float4 f = src[i];
    bf16x4 o;
    o[0] = (bf16)f.x; o[1] = (bf16)f.y; o[2] = (bf16)f.z; o[3] = (bf16)f.w;
    dst[i] = o;
  }
}

__global__ __launch_bounds__(256) void init_x_kernel(
    const float4* __restrict__ src, float4* __restrict__ xf,
    bf16x4* __restrict__ xb, int n4)
{
  int i = blockIdx.x*blockDim.x + threadIdx.x;
  const int stride = gridDim.x*blockDim.x;
  for (; i < n4; i += stride) {
    float4 f = src[i];
    xf[i] = f;
    bf16x4 o;
    o[0] = (bf16)f.x; o[1] = (bf16)f.y; o[2] = (bf16)f.z; o[3] = (bf16)f.w;
    xb[i] = o;
  }
}

// ---------------------------------------------------------------------------
extern "C" void kernel_launch(void* const* d_in, const int* in_sizes, int n_in,
                              void* d_out, int out_size, void* d_ws, size_t ws_size,
                              hipStream_t stream) {
  const float* x    = (const float*)d_in[0];
  const float* inw  = (const float*)d_in[1];
  const float* inb  = (const float*)d_in[2];
  const float* outw = (const float*)d_in[3];
  const float* outb = (const float*)d_in[4];
  const float* ln1w = (const float*)d_in[5];
  const float* ln1b = (const float*)d_in[6];
  const float* l1w  = (const float*)d_in[7];
  const float* l1b  = (const float*)d_in[8];
  const float* l2w  = (const float*)d_in[9];
  const float* l2b  = (const float*)d_in[10];
  const float* ln2w = (const float*)d_in[11];
  const float* ln2b = (const float*)d_in[12];

  char* ws = (char*)d_ws;
  size_t off = 0;
  auto take = [&](size_t bytes) {
    char* p = ws + off;
    off = (off + bytes + 255) & ~(size_t)255;
    return p;
  };
  bf16*  w_in_bf  = (bf16*) take((size_t)NL_*3*D_*D_*2);
  bf16*  w_out_bf = (bf16*) take((size_t)NL_*D_*D_*2);
  bf16*  w_l1_bf  = (bf16*) take((size_t)NL_*DFF_*D_*2);
  bf16*  w_l2_bf  = (bf16*) take((size_t)NL_*D_*DFF_*2);
  float* x_f      = (float*)take((size_t)M_*D_*4);
  bf16*  x_b      = (bf16*) take((size_t)M_*D_*2);
  bf16*  qkv_b    = (bf16*) take((size_t)M_*3*D_*2);
  bf16*  vt_b     = (bf16*) take((size_t)B_*H_*DH_*S_*2);
  bf16*  at_b     = (bf16*) take((size_t)M_*D_*2);
  bf16*  h_b      = (bf16*) take((size_t)M_*DFF_*2);
  bf16*  parts    = (bf16*) take((size_t)4*M_*D_*2);   // 4 bf16 partials
  (void)ws_size; (void)in_sizes; (void)n_in;

  auto conv = [&](const float* s, bf16* d, size_t n) {
    int n4 = (int)(n >> 2);
    int grid = (n4 + 255) / 256; if (grid > 4096) grid = 4096;
    conv_kernel<<<grid, 256, 0, stream>>>((const float4*)s, (bf16x4*)d, n4);
  };
  conv(inw,  w_in_bf,  (size_t)NL_*3*D_*D_);
  conv(outw, w_out_bf, (size_t)NL_*D_*D_);
  conv(l1w,  w_l1_bf,  (size_t)NL_*DFF_*D_);
  conv(l2w,  w_l2_bf,  (size_t)NL_*D_*DFF_);
  init_x_kernel<<<4096, 256, 0, stream>>>((const float4*)x, (float4*)x_f,
                                          (bf16x4*)x_b, (int)((size_t)M_*D_ >> 2));

  for (int l = 0; l < NL_; ++l) {
    // qkv = x @ in_proj_w^T + b [4096,3072]; 256^2 pipelined, 192 blocks;
    // V third -> Vt transposed
    gemm256_kernel<0,1,1><<<192, 512, 0, stream>>>(
        x_b, w_in_bf + (size_t)l*3*D_*D_, inb + (size_t)l*3*D_,
        qkv_b, vt_b, 3*D_, D_, D_, 12, 3, 8, 192);
    // attention -> at_b [4096,1024] bf16; 512 balanced blocks (qb pair/block)
    attn_kernel<<<512, 256, 0, stream>>>(qkv_b, vt_b, at_b);
    // o partials = attn @ out_w^T  (128^2 split-K=2, BK=64, grid 512)
    gemm_bt_kernel<0,2,64><<<512, 256, 0, stream>>>(
        at_b, w_out_bf + (size_t)l*D_*D_, nullptr,
        parts, D_, D_, D_/2, 8, 4, 8, 256);
    // x = LN(x + parts0 + parts1 + out_b)
    add_ln_kernel<2><<<M_, 256, 0, stream>>>(
        x_f, parts, outb + (size_t)l*D_,
        ln1w + (size_t)l*D_, ln1b + (size_t)l*D_, x_f, x_b, nullptr);
    // h = relu(x @ lin1^T + b) [4096,4096]; 256^2 pipelined, 256 blocks
    gemm256_kernel<1,1,0><<<256, 512, 0, stream>>>(
        x_b, w_l1_bf + (size_t)l*DFF_*D_, l1b + (size_t)l*DFF_,
        h_b, nullptr, DFF_, D_, D_, 16, 4, 8, 256);
    // f partials = h @ lin2^T  (256^2 split-K=4, Kc=1024, 256 blocks)
    gemm256_kernel<0,2,0><<<256, 512, 0, stream>>>(
        h_b, w_l2_bf + (size_t)l*D_*DFF_, nullptr,
        parts, nullptr, D_, DFF_, DFF_/4, 4, 1, 8, 64);
    // x = LN(x + parts0..3 + lin2_b); last layer writes d_out
    add_ln_kernel<4><<<M_, 256, 0, stream>>>(
        x_f, parts, l2b + (size_t)l*D_,
        ln2w + (size_t)l*D_, ln2b + (size_t)l*D_, x_f, x_b,
        (l == NL_-1) ? (float*)d_out : nullptr);
  }
}